// Round 5
// baseline (220.861 us; speedup 1.0000x reference)
//
#include <hip/hip_runtime.h>

#define THREADS 256

typedef float f4 __attribute__((ext_vector_type(4)));

__device__ __forceinline__ void row9(
    float e0, float e1, float e2, float e3, float e4,
    float e5, float e6, float e7, float e8,
    float xt, float w, float& lsum, float& lcnt)
{
    float m = fmaxf(fmaxf(fmaxf(e0, e1), fmaxf(e2, e3)),
                    fmaxf(fmaxf(e4, e5), fmaxf(e6, e7)));
    m = fmaxf(m, e8);
    float s = __expf(e0 - m) + __expf(e1 - m) + __expf(e2 - m) + __expf(e3 - m)
            + __expf(e4 - m) + __expf(e5 - m) + __expf(e6 - m) + __expf(e7 - m)
            + __expf(e8 - m);
    const float loss = -w * (xt - m - __logf(s));
    lsum += loss;
    lcnt += (loss > 1e-16f) ? 1.0f : 0.0f;
}

__global__ __launch_bounds__(THREADS) void ce_main_kernel(
    const float* __restrict__ logits,
    const int*   __restrict__ target,
    const float* __restrict__ cw,
    float2*      __restrict__ partials,   // one (sum,count) per block
    int N)
{
    __shared__ float rsum[THREADS / 64];
    __shared__ float rcnt[THREADS / 64];

    const int tid = blockIdx.x * THREADS + threadIdx.x;
    const int r0  = tid * 4;              // 4 consecutive rows per thread

    float lsum = 0.0f, lcnt = 0.0f;

    if (r0 + 3 < N) {
        // All loads independent, issued up front: 1x int4 + 9x dwordx4 (16-B aligned: 144 B/thread)
        const int4 tg = *(const int4*)(target + r0);
        const f4* __restrict__ p = (const f4*)(logits + (size_t)r0 * 9);
        const f4 v0 = p[0], v1 = p[1], v2 = p[2], v3 = p[3], v4 = p[4],
                 v5 = p[5], v6 = p[6], v7 = p[7], v8 = p[8];

        // Gathers depend only on tg; lines already L1-resident from the vector loads.
        const float* __restrict__ row = logits + (size_t)r0 * 9;
        const float xt0 = row[tg.x];
        const float xt1 = row[9  + tg.y];
        const float xt2 = row[18 + tg.z];
        const float xt3 = row[27 + tg.w];
        const float w0 = cw[tg.x], w1 = cw[tg.y], w2 = cw[tg.z], w3 = cw[tg.w];

        // Static component indexing only (no scratch):
        row9(v0.x, v0.y, v0.z, v0.w, v1.x, v1.y, v1.z, v1.w, v2.x, xt0, w0, lsum, lcnt);
        row9(v2.y, v2.z, v2.w, v3.x, v3.y, v3.z, v3.w, v4.x, v4.y, xt1, w1, lsum, lcnt);
        row9(v4.z, v4.w, v5.x, v5.y, v5.z, v5.w, v6.x, v6.y, v6.z, xt2, w2, lsum, lcnt);
        row9(v6.w, v7.x, v7.y, v7.z, v7.w, v8.x, v8.y, v8.z, v8.w, xt3, w3, lsum, lcnt);
    } else if (r0 < N) {
        // tail: per-row scalar path (not taken for N % 4 == 0)
        for (int r = r0; r < N && r < r0 + 4; ++r) {
            const float* __restrict__ x = logits + (size_t)r * 9;
            const int t = target[r];
            row9(x[0], x[1], x[2], x[3], x[4], x[5], x[6], x[7], x[8],
                 x[t], cw[t], lsum, lcnt);
        }
    }

    // 64-lane wave reduction
    #pragma unroll
    for (int off = 32; off > 0; off >>= 1) {
        lsum += __shfl_down(lsum, off);
        lcnt += __shfl_down(lcnt, off);
    }
    const int wave = threadIdx.x >> 6;
    if ((threadIdx.x & 63) == 0) { rsum[wave] = lsum; rcnt[wave] = lcnt; }
    __syncthreads();
    if (threadIdx.x == 0) {
        float bs = 0.0f, bc = 0.0f;
        #pragma unroll
        for (int w2 = 0; w2 < THREADS / 64; ++w2) { bs += rsum[w2]; bc += rcnt[w2]; }
        partials[blockIdx.x] = make_float2(bs, bc);   // no atomics
    }
}

__global__ __launch_bounds__(THREADS) void ce_finalize_kernel(
    const float2* __restrict__ partials, float* __restrict__ out,
    int nPartials, float invN)
{
    __shared__ float rsum[THREADS / 64];
    __shared__ float rcnt[THREADS / 64];
    const int t = threadIdx.x;
    float s = 0.0f, c = 0.0f;
    for (int i = t; i < nPartials; i += THREADS) {
        const float2 p = partials[i];
        s += p.x; c += p.y;
    }
    #pragma unroll
    for (int off = 32; off > 0; off >>= 1) {
        s += __shfl_down(s, off);
        c += __shfl_down(c, off);
    }
    const int wave = t >> 6;
    if ((t & 63) == 0) { rsum[wave] = s; rcnt[wave] = c; }
    __syncthreads();
    if (t == 0) {
        float S = 0.0f, C = 0.0f;
        #pragma unroll
        for (int w2 = 0; w2 < THREADS / 64; ++w2) { S += rsum[w2]; C += rcnt[w2]; }
        out[0] = S / (C + 1e-16f);   // mean over nonzero losses
        out[1] = S * invN;           // plain mean
    }
}

extern "C" void kernel_launch(void* const* d_in, const int* in_sizes, int n_in,
                              void* d_out, int out_size, void* d_ws, size_t ws_size,
                              hipStream_t stream) {
    const float* logits = (const float*)d_in[0];
    const int*   target = (const int*)d_in[1];
    const float* cw     = (const float*)d_in[2];
    float* out = (float*)d_out;
    float2* partials = (float2*)d_ws;

    const int N = in_sizes[1];                       // row count
    const int nThreadsNeeded = (N + 3) / 4;          // 4 rows per thread
    int grid = (nThreadsNeeded + THREADS - 1) / THREADS;
    const int maxByWs = (int)(ws_size / sizeof(float2));
    if (grid > maxByWs) grid = maxByWs;              // safety (ws is far larger in practice)

    ce_main_kernel<<<grid, THREADS, 0, stream>>>(logits, target, cw, partials, N);
    ce_finalize_kernel<<<1, THREADS, 0, stream>>>(partials, out, grid, 1.0f / (float)N);
}

// Round 7
// 218.741 us; speedup vs baseline: 1.0097x; 1.0097x over previous
//
#include <hip/hip_runtime.h>

#define THREADS 256

typedef float f4 __attribute__((ext_vector_type(4)));

// 9-way select with static operands only (no scratch, rule #20).
// Compiler shares the v_cmp results between paired selects in the caller.
__device__ __forceinline__ float sel9(int tg,
    float a0, float a1, float a2, float a3, float a4,
    float a5, float a6, float a7, float a8)
{
    float r = a0;
    r = (tg == 1) ? a1 : r;
    r = (tg == 2) ? a2 : r;
    r = (tg == 3) ? a3 : r;
    r = (tg == 4) ? a4 : r;
    r = (tg == 5) ? a5 : r;
    r = (tg == 6) ? a6 : r;
    r = (tg == 7) ? a7 : r;
    r = (tg == 8) ? a8 : r;
    return r;
}

__device__ __forceinline__ void row9(
    float e0, float e1, float e2, float e3, float e4,
    float e5, float e6, float e7, float e8,
    int tg, float w, float& lsum, float& lcnt)
{
    const float xt = sel9(tg, e0, e1, e2, e3, e4, e5, e6, e7, e8);
    float m = fmaxf(fmaxf(fmaxf(e0, e1), fmaxf(e2, e3)),
                    fmaxf(fmaxf(e4, e5), fmaxf(e6, e7)));
    m = fmaxf(m, e8);
    float s = __expf(e0 - m) + __expf(e1 - m) + __expf(e2 - m) + __expf(e3 - m)
            + __expf(e4 - m) + __expf(e5 - m) + __expf(e6 - m) + __expf(e7 - m)
            + __expf(e8 - m);
    const float loss = -w * (xt - m - __logf(s));
    lsum += loss;
    lcnt += (loss > 1e-16f) ? 1.0f : 0.0f;
}

__global__ __launch_bounds__(THREADS) void ce_main_kernel(
    const float* __restrict__ logits,
    const int*   __restrict__ target,
    const float* __restrict__ cw,
    float2*      __restrict__ partials,   // one (sum,count) per block
    int N)
{
    __shared__ float rsum[THREADS / 64];
    __shared__ float rcnt[THREADS / 64];

    // class weights: uniform address -> scalar loads, live in SGPRs
    const float w0 = cw[0], w1 = cw[1], w2 = cw[2], w3 = cw[3], w4 = cw[4],
                w5 = cw[5], w6 = cw[6], w7 = cw[7], w8 = cw[8];

    const int tid = blockIdx.x * THREADS + threadIdx.x;
    const int r0  = tid * 4;              // 4 consecutive rows per thread

    float lsum = 0.0f, lcnt = 0.0f;

    if (r0 + 3 < N) {
        // 10 independent loads, one wait point, zero dependent gathers.
        const int4 tg = *(const int4*)(target + r0);
        const f4* __restrict__ p = (const f4*)(logits + (size_t)r0 * 9);
        const f4 v0 = p[0], v1 = p[1], v2 = p[2], v3 = p[3], v4 = p[4],
                 v5 = p[5], v6 = p[6], v7 = p[7], v8 = p[8];

        const float wa = sel9(tg.x, w0, w1, w2, w3, w4, w5, w6, w7, w8);
        const float wb = sel9(tg.y, w0, w1, w2, w3, w4, w5, w6, w7, w8);
        const float wc = sel9(tg.z, w0, w1, w2, w3, w4, w5, w6, w7, w8);
        const float wd = sel9(tg.w, w0, w1, w2, w3, w4, w5, w6, w7, w8);

        row9(v0.x, v0.y, v0.z, v0.w, v1.x, v1.y, v1.z, v1.w, v2.x, tg.x, wa, lsum, lcnt);
        row9(v2.y, v2.z, v2.w, v3.x, v3.y, v3.z, v3.w, v4.x, v4.y, tg.y, wb, lsum, lcnt);
        row9(v4.z, v4.w, v5.x, v5.y, v5.z, v5.w, v6.x, v6.y, v6.z, tg.z, wc, lsum, lcnt);
        row9(v6.w, v7.x, v7.y, v7.z, v7.w, v8.x, v8.y, v8.z, v8.w, tg.w, wd, lsum, lcnt);
    } else if (r0 < N) {
        // tail (not taken for N % 4 == 0): scalar per-row path
        for (int r = r0; r < N && r < r0 + 4; ++r) {
            const float* __restrict__ x = logits + (size_t)r * 9;
            const int t = target[r];
            const float w = sel9(t, w0, w1, w2, w3, w4, w5, w6, w7, w8);
            row9(x[0], x[1], x[2], x[3], x[4], x[5], x[6], x[7], x[8],
                 t, w, lsum, lcnt);
        }
    }

    // 64-lane wave reduction
    #pragma unroll
    for (int off = 32; off > 0; off >>= 1) {
        lsum += __shfl_down(lsum, off);
        lcnt += __shfl_down(lcnt, off);
    }
    const int wave = threadIdx.x >> 6;
    if ((threadIdx.x & 63) == 0) { rsum[wave] = lsum; rcnt[wave] = lcnt; }
    __syncthreads();
    if (threadIdx.x == 0) {
        float bs = 0.0f, bc = 0.0f;
        #pragma unroll
        for (int w2 = 0; w2 < THREADS / 64; ++w2) { bs += rsum[w2]; bc += rcnt[w2]; }
        partials[blockIdx.x] = make_float2(bs, bc);   // no atomics
    }
}

__global__ __launch_bounds__(THREADS) void ce_finalize_kernel(
    const float2* __restrict__ partials, float* __restrict__ out,
    int nPartials, float invN)
{
    __shared__ float rsum[THREADS / 64];
    __shared__ float rcnt[THREADS / 64];
    const int t = threadIdx.x;
    float s = 0.0f, c = 0.0f;
    for (int i = t; i < nPartials; i += THREADS) {
        const float2 p = partials[i];
        s += p.x; c += p.y;
    }
    #pragma unroll
    for (int off = 32; off > 0; off >>= 1) {
        s += __shfl_down(s, off);
        c += __shfl_down(c, off);
    }
    const int wave = t >> 6;
    if ((t & 63) == 0) { rsum[wave] = s; rcnt[wave] = c; }
    __syncthreads();
    if (t == 0) {
        float S = 0.0f, C = 0.0f;
        #pragma unroll
        for (int w2 = 0; w2 < THREADS / 64; ++w2) { S += rsum[w2]; C += rcnt[w2]; }
        out[0] = S / (C + 1e-16f);   // mean over nonzero losses
        out[1] = S * invN;           // plain mean
    }
}

extern "C" void kernel_launch(void* const* d_in, const int* in_sizes, int n_in,
                              void* d_out, int out_size, void* d_ws, size_t ws_size,
                              hipStream_t stream) {
    const float* logits = (const float*)d_in[0];
    const int*   target = (const int*)d_in[1];
    const float* cw     = (const float*)d_in[2];
    float* out = (float*)d_out;
    float2* partials = (float2*)d_ws;

    const int N = in_sizes[1];                       // row count
    const int nThreadsNeeded = (N + 3) / 4;          // 4 rows per thread
    int grid = (nThreadsNeeded + THREADS - 1) / THREADS;
    const int maxByWs = (int)(ws_size / sizeof(float2));
    if (grid > maxByWs) grid = maxByWs;              // safety (ws is far larger in practice)

    ce_main_kernel<<<grid, THREADS, 0, stream>>>(logits, target, cw, partials, N);
    ce_finalize_kernel<<<1, THREADS, 0, stream>>>(partials, out, grid, 1.0f / (float)N);
}